// Round 5
// baseline (472.310 us; speedup 1.0000x reference)
//
#include <hip/hip_runtime.h>
#include <hip/hip_bf16.h>
#include <math.h>

constexpr int B_ = 8, L_ = 256, D_ = 256, H_ = 8, DK_ = 32, NL_ = 4, V_ = 2048, FF_ = 1024;
constexpr int N_ = B_ * L_;
constexpr float EPS_ = 1e-5f;

typedef short bf16x8 __attribute__((ext_vector_type(8)));
typedef float f32x4 __attribute__((ext_vector_type(4)));
typedef _Float16 f16x4 __attribute__((ext_vector_type(4)));

__device__ __forceinline__ short f2b(float f) {
    union { __hip_bfloat16 h; short s; } u;
    u.h = __float2bfloat16(f);
    return u.s;
}

// x[n,d] = value_tab[tok]*sqrt(D) + coord_tab[p%3] + pos_tab[p/3]  (fp32 residual stream)
__global__ void embed_kernel(const int* __restrict__ tokens, const int* __restrict__ positions,
                             const float* __restrict__ vtab, const float* __restrict__ ctab,
                             const float* __restrict__ ptab, float* __restrict__ x) {
    int n = blockIdx.x, d = threadIdx.x;
    int tok = tokens[n], p = positions[n];
    x[n * D_ + d] = vtab[tok * D_ + d] * 16.0f + ctab[(p % 3) * D_ + d] + ptab[(p / 3) * D_ + d];
}

// LayerNorm, writes bf16 (all consumers are MFMA GEMMs)
__global__ void ln_kernel(const float* __restrict__ x, const float* __restrict__ g,
                          const float* __restrict__ b, short* __restrict__ out) {
    __shared__ float r1[4], r2[4], mv[2];
    int n = blockIdx.x, t = threadIdx.x;
    float v = x[n * D_ + t];
    float s1 = v, s2 = v * v;
#pragma unroll
    for (int off = 32; off; off >>= 1) {
        s1 += __shfl_down(s1, off, 64);
        s2 += __shfl_down(s2, off, 64);
    }
    int w = t >> 6;
    if ((t & 63) == 0) { r1[w] = s1; r2[w] = s2; }
    __syncthreads();
    if (t == 0) {
        float a = r1[0] + r1[1] + r1[2] + r1[3];
        float c = r2[0] + r2[1] + r2[2] + r2[3];
        float mean = a * (1.0f / D_);
        float var = c * (1.0f / D_) - mean * mean;
        mv[0] = mean;
        mv[1] = rsqrtf(var + EPS_);
    }
    __syncthreads();
    out[n * D_ + t] = f2b((v - mv[0]) * mv[1] * g[t] + b[t]);
}

// fp32 [K,N] -> bf16 [N,K] tiled transpose; batch via blockIdx.z
__global__ void transpose_w(const float* __restrict__ src, short* __restrict__ dst, int K, int Nn) {
    __shared__ float tile[32][33];
    int n0 = blockIdx.x * 32, k0 = blockIdx.y * 32;
    size_t base = (size_t)blockIdx.z * K * Nn;
    src += base;
    dst += base;
    int tx = threadIdx.x, ty = threadIdx.y;  // 32 x 8
#pragma unroll
    for (int i = 0; i < 32; i += 8)
        tile[ty + i][tx] = src[(size_t)(k0 + ty + i) * Nn + n0 + tx];
    __syncthreads();
#pragma unroll
    for (int i = 0; i < 32; i += 8)
        dst[(size_t)(n0 + ty + i) * K + k0 + tx] = f2b(tile[tx][ty + i]);
}

// all four DxD weight families in one launch: z = layer*4 + matrix
__global__ void transpose_w4(const float* __restrict__ Wq, const float* __restrict__ Wk,
                             const float* __restrict__ Wv, const float* __restrict__ Wo,
                             short* __restrict__ wqT, short* __restrict__ wkT,
                             short* __restrict__ wvT, short* __restrict__ woT) {
    __shared__ float tile[32][33];
    int z = blockIdx.z, m = z & 3, layer = z >> 2;
    const float* src = (m == 0) ? Wq : (m == 1) ? Wk : (m == 2) ? Wv : Wo;
    short* dst = (m == 0) ? wqT : (m == 1) ? wkT : (m == 2) ? wvT : woT;
    src += (size_t)layer * D_ * D_;
    dst += (size_t)layer * D_ * D_;
    int n0 = blockIdx.x * 32, k0 = blockIdx.y * 32;
    int tx = threadIdx.x, ty = threadIdx.y;
#pragma unroll
    for (int i = 0; i < 32; i += 8)
        tile[ty + i][tx] = src[(size_t)(k0 + ty + i) * D_ + n0 + tx];
    __syncthreads();
#pragma unroll
    for (int i = 0; i < 32; i += 8)
        dst[(size_t)(n0 + ty + i) * D_ + k0 + tx] = f2b(tile[tx][ty + i]);
}

// 64x64 tile bf16 MFMA GEMM body. A:[M,K] bf16 row-major, Bt:[Nout,K] bf16 row-major.
// BK-chunked LDS staging with register prefetch; padded stride (BK+8) kills bank conflicts.
// EPI: 0 = store fp32; 1 = bias+relu -> bf16; 2 = atomicAdd fp32 (+bias from kz==0);
//      3 = bias -> fp32; 4 = store bf16; 5 = store f16
template <int EPI, bool HAS_BIAS, int BK>
__device__ __forceinline__ void gemm_body(const short* __restrict__ A, const short* __restrict__ Bt,
                                          const float* __restrict__ bias, float* __restrict__ Cf,
                                          short* __restrict__ Cb, int M, int K, int Nout,
                                          int kbeg, int kend, int kz) {
    constexpr int NI = BK / 32;        // int4 loads per thread per matrix
    constexpr int STRIDE = BK + 8;     // shorts; (BK+8)*2 bytes is 16B-aligned for BK%32==0
    __shared__ short As[64][STRIDE];
    __shared__ short Bs[64][STRIDE];
    int t = threadIdx.x;
    int m0 = blockIdx.x * 64, n0 = blockIdx.y * 64;
    int sr = t >> 2, sc = (t & 3) * (BK / 4);
    int lane = t & 63, w = t >> 6;
    int mo = (w & 1) * 32, no = (w >> 1) * 32;
    int quad = lane >> 4, r = lane & 15;
    f32x4 acc00 = {}, acc01 = {}, acc10 = {}, acc11 = {};
    const short* Ap = &A[(size_t)(m0 + sr) * K + sc];
    const short* Bp = &Bt[(size_t)(n0 + sr) * K + sc];
    int4 aR[NI], bR[NI];
#pragma unroll
    for (int i = 0; i < NI; ++i) {
        aR[i] = *(const int4*)(Ap + kbeg + i * 8);
        bR[i] = *(const int4*)(Bp + kbeg + i * 8);
    }
    for (int k0 = kbeg; k0 < kend; k0 += BK) {
        __syncthreads();
#pragma unroll
        for (int i = 0; i < NI; ++i) {
            *(int4*)&As[sr][sc + i * 8] = aR[i];
            *(int4*)&Bs[sr][sc + i * 8] = bR[i];
        }
        __syncthreads();
        if (k0 + BK < kend) {
#pragma unroll
            for (int i = 0; i < NI; ++i) {
                aR[i] = *(const int4*)(Ap + k0 + BK + i * 8);
                bR[i] = *(const int4*)(Bp + k0 + BK + i * 8);
            }
        }
#pragma unroll
        for (int kk = 0; kk < BK; kk += 32) {
            bf16x8 a0 = *(const bf16x8*)&As[mo + r][kk + quad * 8];
            bf16x8 a1 = *(const bf16x8*)&As[mo + 16 + r][kk + quad * 8];
            bf16x8 b0 = *(const bf16x8*)&Bs[no + r][kk + quad * 8];
            bf16x8 b1 = *(const bf16x8*)&Bs[no + 16 + r][kk + quad * 8];
            acc00 = __builtin_amdgcn_mfma_f32_16x16x32_bf16(a0, b0, acc00, 0, 0, 0);
            acc01 = __builtin_amdgcn_mfma_f32_16x16x32_bf16(a0, b1, acc01, 0, 0, 0);
            acc10 = __builtin_amdgcn_mfma_f32_16x16x32_bf16(a1, b0, acc10, 0, 0, 0);
            acc11 = __builtin_amdgcn_mfma_f32_16x16x32_bf16(a1, b1, acc11, 0, 0, 0);
        }
    }
#pragma unroll
    for (int i = 0; i < 2; ++i) {
#pragma unroll
        for (int j = 0; j < 2; ++j) {
            f32x4 acc = (i == 0) ? (j == 0 ? acc00 : acc01) : (j == 0 ? acc10 : acc11);
            int col = n0 + no + j * 16 + r;
            float bval = HAS_BIAS ? bias[col] : 0.f;
#pragma unroll
            for (int p = 0; p < 4; ++p) {
                int row = m0 + mo + i * 16 + quad * 4 + p;
                float v = acc[p];
                if (EPI == 0) {
                    Cf[(size_t)row * Nout + col] = v;
                } else if (EPI == 1) {
                    Cb[(size_t)row * Nout + col] = f2b(fmaxf(v + bval, 0.f));
                } else if (EPI == 2) {
                    float add = v + ((HAS_BIAS && kz == 0) ? bval : 0.f);
                    atomicAdd(&Cf[(size_t)row * Nout + col], add);
                } else if (EPI == 3) {
                    Cf[(size_t)row * Nout + col] = v + bval;
                } else if (EPI == 4) {
                    Cb[(size_t)row * Nout + col] = f2b(v);
                } else {
                    ((_Float16*)Cb)[(size_t)row * Nout + col] = (_Float16)v;
                }
            }
        }
    }
}

// fused Q/K/V projection: q,k -> bf16; v -> f16 (PV mfma uses f16)
__global__ __launch_bounds__(256) void gemm_qkv(const short* __restrict__ A, const short* __restrict__ wq,
                                                const short* __restrict__ wk, const short* __restrict__ wv,
                                                short* __restrict__ q, short* __restrict__ k,
                                                short* __restrict__ v, int M, int K, int Nout) {
    if (blockIdx.z == 0)
        gemm_body<4, false, 128>(A, wq, nullptr, nullptr, q, M, K, Nout, 0, K, 0);
    else if (blockIdx.z == 1)
        gemm_body<4, false, 128>(A, wk, nullptr, nullptr, k, M, K, Nout, 0, K, 0);
    else
        gemm_body<5, false, 128>(A, wv, nullptr, nullptr, v, M, K, Nout, 0, K, 0);
}

template <int SPLITK, bool HAS_BIAS, int BK>
__global__ __launch_bounds__(256) void gemm_accum(const short* __restrict__ A, const short* __restrict__ Bt,
                                                  const float* __restrict__ bias, float* __restrict__ C,
                                                  int M, int K, int Nout) {
    int Kp = K / SPLITK;
    int kz = blockIdx.z;
    gemm_body<2, HAS_BIAS, BK>(A, Bt, bias, C, nullptr, M, K, Nout, kz * Kp, kz * Kp + Kp, kz);
}

__global__ __launch_bounds__(256) void gemm_biasrelu_bf16(const short* __restrict__ A,
                                                          const short* __restrict__ Bt,
                                                          const float* __restrict__ bias,
                                                          short* __restrict__ C, int M, int K, int Nout) {
    gemm_body<1, true, 128>(A, Bt, bias, nullptr, C, M, K, Nout, 0, K, 0);
}

__global__ __launch_bounds__(256) void gemm_bias(const short* __restrict__ A, const short* __restrict__ Bt,
                                                 const float* __restrict__ bias, float* __restrict__ C,
                                                 int M, int K, int Nout) {
    gemm_body<3, true, 128>(A, Bt, bias, C, nullptr, M, K, Nout, 0, K, 0);
}

// MFMA flash attention. One wave (64 thr) per (b,h,q-tile of 16 queries).
// S^T = K·Q^T via mfma_16x16x32_bf16 -> C layout (q=lane&15, src=quad*4+reg)
// which IS the A-layout of mfma_16x16x16f16 -> PV with no transpose.
__global__ __launch_bounds__(64) void attn_kernel(const short* __restrict__ q,
                                                  const short* __restrict__ k,
                                                  const _Float16* __restrict__ v,
                                                  short* __restrict__ z) {
    int blk = blockIdx.x;
    int bh = blk & 63;
    int qt = 15 - (blk >> 6);  // heavy q-tiles dispatched first
    int b = bh >> 3, h = bh & 7;
    int lane = threadIdx.x;
    int r = lane & 15, quad = lane >> 4;
    int row0 = b * L_;

    bf16x8 qf = *(const bf16x8*)&q[(size_t)(row0 + qt * 16 + r) * D_ + h * DK_ + quad * 8];
    f32x4 O0 = {}, O1 = {};
    float mA = -1e30f, den = 0.f;
    int nk = qt + 1;

    bf16x8 kf = *(const bf16x8*)&k[(size_t)(row0 + r) * D_ + h * DK_ + quad * 8];
    f16x4 va, vb;
    {
        const _Float16* vp = v + (size_t)(row0 + quad * 4) * D_ + h * DK_;
#pragma unroll
        for (int i = 0; i < 4; ++i) {
            va[i] = vp[(size_t)i * D_ + r];
            vb[i] = vp[(size_t)i * D_ + 16 + r];
        }
    }
    for (int kt = 0; kt < nk; ++kt) {
        bf16x8 kf_n = kf;
        f16x4 va_n = va, vb_n = vb;
        if (kt + 1 < nk) {
            kf_n = *(const bf16x8*)&k[(size_t)(row0 + (kt + 1) * 16 + r) * D_ + h * DK_ + quad * 8];
            const _Float16* vp = v + (size_t)(row0 + (kt + 1) * 16 + quad * 4) * D_ + h * DK_;
#pragma unroll
            for (int i = 0; i < 4; ++i) {
                va_n[i] = vp[(size_t)i * D_ + r];
                vb_n[i] = vp[(size_t)i * D_ + 16 + r];
            }
        }
        f32x4 zero = {};
        f32x4 s = __builtin_amdgcn_mfma_f32_16x16x32_bf16(kf, qf, zero, 0, 0, 0);
#pragma unroll
        for (int i2 = 0; i2 < 4; ++i2) s[i2] *= 0.17677669529663687f;
        if (kt == qt) {
#pragma unroll
            for (int i2 = 0; i2 < 4; ++i2)
                if (quad * 4 + i2 > r) s[i2] = -1e30f;
        }
        float tmax = fmaxf(fmaxf(s[0], s[1]), fmaxf(s[2], s[3]));
        tmax = fmaxf(tmax, __shfl_xor(tmax, 16, 64));
        tmax = fmaxf(tmax, __shfl_xor(tmax, 32, 64));
        float mn = fmaxf(mA, tmax);
        float alpha = __expf(mA - mn);
        mA = mn;
        float p0 = __expf(s[0] - mn), p1 = __expf(s[1] - mn);
        float p2 = __expf(s[2] - mn), p3 = __expf(s[3] - mn);
        float ts = (p0 + p1) + (p2 + p3);
        ts += __shfl_xor(ts, 16, 64);
        ts += __shfl_xor(ts, 32, 64);
        den = den * alpha + ts;
        f16x4 pf;
        pf[0] = (_Float16)p0; pf[1] = (_Float16)p1; pf[2] = (_Float16)p2; pf[3] = (_Float16)p3;
        float al[4];
#pragma unroll
        for (int i2 = 0; i2 < 4; ++i2) al[i2] = __shfl(alpha, quad * 4 + i2, 64);
#pragma unroll
        for (int i2 = 0; i2 < 4; ++i2) { O0[i2] *= al[i2]; O1[i2] *= al[i2]; }
        O0 = __builtin_amdgcn_mfma_f32_16x16x16f16(pf, va, O0, 0, 0, 0);
        O1 = __builtin_amdgcn_mfma_f32_16x16x16f16(pf, vb, O1, 0, 0, 0);
        kf = kf_n; va = va_n; vb = vb_n;
    }
#pragma unroll
    for (int i2 = 0; i2 < 4; ++i2) {
        float inv = 1.0f / __shfl(den, quad * 4 + i2, 64);
        int rowz = row0 + qt * 16 + quad * 4 + i2;
        z[(size_t)rowz * D_ + h * DK_ + r] = f2b(O0[i2] * inv);
        z[(size_t)rowz * D_ + h * DK_ + 16 + r] = f2b(O1[i2] * inv);
    }
}

// in-place log_softmax over V=2048, one block per row
__global__ void lsm_kernel(float* __restrict__ logits) {
    __shared__ float rm[4], rs[4];
    int row = blockIdx.x, t = threadIdx.x;
    float* p = logits + (size_t)row * V_;
    float vals[8];
    float mx = -INFINITY;
#pragma unroll
    for (int i = 0; i < 8; ++i) {
        vals[i] = p[t + i * 256];
        mx = fmaxf(mx, vals[i]);
    }
#pragma unroll
    for (int off = 32; off; off >>= 1) mx = fmaxf(mx, __shfl_xor(mx, off, 64));
    int w = t >> 6;
    if ((t & 63) == 0) rm[w] = mx;
    __syncthreads();
    mx = fmaxf(fmaxf(rm[0], rm[1]), fmaxf(rm[2], rm[3]));
    float s = 0.f;
#pragma unroll
    for (int i = 0; i < 8; ++i) s += __expf(vals[i] - mx);
#pragma unroll
    for (int off = 32; off; off >>= 1) s += __shfl_xor(s, off, 64);
    if ((t & 63) == 0) rs[w] = s;
    __syncthreads();
    s = rs[0] + rs[1] + rs[2] + rs[3];
    float lse = mx + logf(s);
#pragma unroll
    for (int i = 0; i < 8; ++i) p[t + i * 256] = vals[i] - lse;
}

extern "C" void kernel_launch(void* const* d_in, const int* in_sizes, int n_in,
                              void* d_out, int out_size, void* d_ws, size_t ws_size,
                              hipStream_t stream) {
    const int* tokens = (const int*)d_in[0];
    const int* positions = (const int*)d_in[1];
    // d_in[2]=src, d_in[3]=dst: deterministic causal structure — unused
    const float* vtab = (const float*)d_in[4];
    const float* ctab = (const float*)d_in[5];
    const float* ptab = (const float*)d_in[6];
    const float* ln1_g = (const float*)d_in[7];
    const float* ln1_b = (const float*)d_in[8];
    const float* Wq = (const float*)d_in[9];
    const float* Wk = (const float*)d_in[10];
    const float* Wv = (const float*)d_in[11];
    const float* Wo = (const float*)d_in[12];
    const float* ln2_g = (const float*)d_in[13];
    const float* ln2_b = (const float*)d_in[14];
    const float* W1 = (const float*)d_in[15];
    const float* b1 = (const float*)d_in[16];
    const float* W2 = (const float*)d_in[17];
    const float* b2 = (const float*)d_in[18];
    const float* lnf_g = (const float*)d_in[19];
    const float* lnf_b = (const float*)d_in[20];
    const float* Wgen = (const float*)d_in[21];
    const float* bgen = (const float*)d_in[22];

    char* p = (char*)d_ws;
    float* x = (float*)p;      p += (size_t)N_ * D_ * 4;
    short* qb = (short*)p;     p += (size_t)N_ * D_ * 4;   // bf16 (padded alloc)
    short* kb = (short*)p;     p += (size_t)N_ * D_ * 4;   // bf16
    short* vbh = (short*)p;    p += (size_t)N_ * D_ * 4;   // f16
    short* xnb = (short*)p;    p += (size_t)N_ * D_ * 2;
    short* zbb = (short*)p;    p += (size_t)N_ * D_ * 2;
    short* hbb = (short*)p;    p += (size_t)N_ * FF_ * 2;
    short* wqT = (short*)p;    p += (size_t)NL_ * D_ * D_ * 2;
    short* wkT = (short*)p;    p += (size_t)NL_ * D_ * D_ * 2;
    short* wvT = (short*)p;    p += (size_t)NL_ * D_ * D_ * 2;
    short* woT = (short*)p;    p += (size_t)NL_ * D_ * D_ * 2;
    short* w1T = (short*)p;    p += (size_t)NL_ * D_ * FF_ * 2;
    short* w2T = (short*)p;    p += (size_t)NL_ * FF_ * D_ * 2;
    short* wgT = (short*)p;    p += (size_t)D_ * V_ * 2;
    float* out = (float*)d_out;

    dim3 tb(32, 8);
    transpose_w4<<<dim3(8, 8, 16), tb, 0, stream>>>(Wq, Wk, Wv, Wo, wqT, wkT, wvT, woT);
    transpose_w<<<dim3(32, 8, NL_), tb, 0, stream>>>(W1, w1T, D_, FF_);
    transpose_w<<<dim3(8, 32, NL_), tb, 0, stream>>>(W2, w2T, FF_, D_);
    transpose_w<<<dim3(64, 8, 1), tb, 0, stream>>>(Wgen, wgT, D_, V_);

    embed_kernel<<<N_, 256, 0, stream>>>(tokens, positions, vtab, ctab, ptab, x);
    dim3 gQKV(N_ / 64, D_ / 64, 3);   // 384 blocks
    dim3 gWo(N_ / 64, D_ / 64, 4);    // 512 blocks, split-K 4 (Kp=64)
    dim3 gW1(N_ / 64, FF_ / 64);      // 512 blocks
    dim3 gW2(N_ / 64, D_ / 64, 8);    // 1024 blocks, split-K 8 (Kp=128)
    dim3 gGen(N_ / 64, V_ / 64);      // 1024 blocks
    for (int i = 0; i < NL_; ++i) {
        ln_kernel<<<N_, 256, 0, stream>>>(x, ln1_g + i * D_, ln1_b + i * D_, xnb);
        gemm_qkv<<<gQKV, 256, 0, stream>>>(xnb, wqT + (size_t)i * D_ * D_, wkT + (size_t)i * D_ * D_,
                                           wvT + (size_t)i * D_ * D_, qb, kb, vbh, N_, D_, D_);
        attn_kernel<<<B_ * H_ * 16, 64, 0, stream>>>(qb, kb, (const _Float16*)vbh, zbb);
        gemm_accum<4, false, 64><<<gWo, 256, 0, stream>>>(zbb, woT + (size_t)i * D_ * D_, nullptr, x, N_, D_, D_);
        ln_kernel<<<N_, 256, 0, stream>>>(x, ln2_g + i * D_, ln2_b + i * D_, xnb);
        gemm_biasrelu_bf16<<<gW1, 256, 0, stream>>>(xnb, w1T + (size_t)i * D_ * FF_, b1 + (size_t)i * FF_,
                                                    hbb, N_, D_, FF_);
        gemm_accum<8, true, 128><<<gW2, 256, 0, stream>>>(hbb, w2T + (size_t)i * FF_ * D_, b2 + (size_t)i * D_,
                                                          x, N_, FF_, D_);
    }
    ln_kernel<<<N_, 256, 0, stream>>>(x, lnf_g, lnf_b, xnb);
    gemm_bias<<<gGen, 256, 0, stream>>>(xnb, wgT, bgen, out, N_, D_, V_);
    lsm_kernel<<<N_, 256, 0, stream>>>(out);
}

// Round 6
// 361.140 us; speedup vs baseline: 1.3078x; 1.3078x over previous
//
#include <hip/hip_runtime.h>
#include <hip/hip_bf16.h>
#include <math.h>

constexpr int B_ = 8, L_ = 256, D_ = 256, H_ = 8, DK_ = 32, NL_ = 4, V_ = 2048, FF_ = 1024;
constexpr int N_ = B_ * L_;
constexpr float EPS_ = 1e-5f;

typedef short bf16x8 __attribute__((ext_vector_type(8)));
typedef float f32x4 __attribute__((ext_vector_type(4)));
typedef _Float16 f16x4 __attribute__((ext_vector_type(4)));

__device__ __forceinline__ short f2b(float f) {
    union { __hip_bfloat16 h; short s; } u;
    u.h = __float2bfloat16(f);
    return u.s;
}

// async 16B/lane global->LDS (global_load_lds_dwordx4). LDS dest = wave-uniform
// base + lane*16 (m97/m104). AS casts via uintptr (CK pattern: low 32 bits of a
// generic LDS pointer are the LDS offset).
__device__ __forceinline__ void load16_lds(const void* g, void* l) {
    auto gp = reinterpret_cast<const __attribute__((address_space(1))) unsigned int*>(
        reinterpret_cast<unsigned long long>(g));
    auto lp = reinterpret_cast<__attribute__((address_space(3))) unsigned int*>(
        (unsigned int)reinterpret_cast<unsigned long long>(l));
    __builtin_amdgcn_global_load_lds(gp, lp, 16, 0, 0);
}

// x[n,d] = value_tab[tok]*sqrt(D) + coord_tab[p%3] + pos_tab[p/3]  (fp32 residual stream)
__global__ void embed_kernel(const int* __restrict__ tokens, const int* __restrict__ positions,
                             const float* __restrict__ vtab, const float* __restrict__ ctab,
                             const float* __restrict__ ptab, float* __restrict__ x) {
    int n = blockIdx.x, d = threadIdx.x;
    int tok = tokens[n], p = positions[n];
    x[n * D_ + d] = vtab[tok * D_ + d] * 16.0f + ctab[(p % 3) * D_ + d] + ptab[(p / 3) * D_ + d];
}

// LayerNorm, writes bf16 (all consumers are MFMA GEMMs)
__global__ void ln_kernel(const float* __restrict__ x, const float* __restrict__ g,
                          const float* __restrict__ b, short* __restrict__ out) {
    __shared__ float r1[4], r2[4], mv[2];
    int n = blockIdx.x, t = threadIdx.x;
    float v = x[n * D_ + t];
    float s1 = v, s2 = v * v;
#pragma unroll
    for (int off = 32; off; off >>= 1) {
        s1 += __shfl_down(s1, off, 64);
        s2 += __shfl_down(s2, off, 64);
    }
    int w = t >> 6;
    if ((t & 63) == 0) { r1[w] = s1; r2[w] = s2; }
    __syncthreads();
    if (t == 0) {
        float a = r1[0] + r1[1] + r1[2] + r1[3];
        float c = r2[0] + r2[1] + r2[2] + r2[3];
        float mean = a * (1.0f / D_);
        float var = c * (1.0f / D_) - mean * mean;
        mv[0] = mean;
        mv[1] = rsqrtf(var + EPS_);
    }
    __syncthreads();
    out[n * D_ + t] = f2b((v - mv[0]) * mv[1] * g[t] + b[t]);
}

// fp32 [K,N] -> bf16 [N,K] tiled transpose; batch via blockIdx.z
__global__ void transpose_w(const float* __restrict__ src, short* __restrict__ dst, int K, int Nn) {
    __shared__ float tile[32][33];
    int n0 = blockIdx.x * 32, k0 = blockIdx.y * 32;
    size_t base = (size_t)blockIdx.z * K * Nn;
    src += base;
    dst += base;
    int tx = threadIdx.x, ty = threadIdx.y;  // 32 x 8
#pragma unroll
    for (int i = 0; i < 32; i += 8)
        tile[ty + i][tx] = src[(size_t)(k0 + ty + i) * Nn + n0 + tx];
    __syncthreads();
#pragma unroll
    for (int i = 0; i < 32; i += 8)
        dst[(size_t)(n0 + ty + i) * K + k0 + tx] = f2b(tile[tx][ty + i]);
}

// all four DxD weight families in one launch: z = layer*4 + matrix
__global__ void transpose_w4(const float* __restrict__ Wq, const float* __restrict__ Wk,
                             const float* __restrict__ Wv, const float* __restrict__ Wo,
                             short* __restrict__ wqT, short* __restrict__ wkT,
                             short* __restrict__ wvT, short* __restrict__ woT) {
    __shared__ float tile[32][33];
    int z = blockIdx.z, m = z & 3, layer = z >> 2;
    const float* src = (m == 0) ? Wq : (m == 1) ? Wk : (m == 2) ? Wv : Wo;
    short* dst = (m == 0) ? wqT : (m == 1) ? wkT : (m == 2) ? wvT : woT;
    src += (size_t)layer * D_ * D_;
    dst += (size_t)layer * D_ * D_;
    int n0 = blockIdx.x * 32, k0 = blockIdx.y * 32;
    int tx = threadIdx.x, ty = threadIdx.y;
#pragma unroll
    for (int i = 0; i < 32; i += 8)
        tile[ty + i][tx] = src[(size_t)(k0 + ty + i) * D_ + n0 + tx];
    __syncthreads();
#pragma unroll
    for (int i = 0; i < 32; i += 8)
        dst[(size_t)(n0 + ty + i) * D_ + k0 + tx] = f2b(tile[tx][ty + i]);
}

// 64x64 tile bf16 MFMA GEMM body. A:[M,K] bf16 row-major, Bt:[Nout,K] bf16 row-major.
// LDS hoisted to caller (single 16 KB allocation). BK=64 chunks staged with
// global_load_lds width=16 (async direct-to-LDS, m97 structure).
// EPI: 0 = store fp32; 1 = bias+relu -> bf16; 2 = atomicAdd fp32 (+bias from kz==0);
//      3 = bias -> fp32; 4 = store bf16; 5 = store f16
template <int EPI, bool HAS_BIAS>
__device__ __forceinline__ void gemm_body(short (*As)[64], short (*Bs)[64],
                                          const short* __restrict__ A, const short* __restrict__ Bt,
                                          const float* __restrict__ bias, float* __restrict__ Cf,
                                          short* __restrict__ Cb, int M, int K, int Nout,
                                          int kbeg, int kend, int kz) {
    int t = threadIdx.x;
    int m0 = blockIdx.x * 64, n0 = blockIdx.y * 64;
    int lane = t & 63, w = t >> 6;
    int mo = (w & 1) * 32, no = (w >> 1) * 32;
    int quad = lane >> 4, r = lane & 15;
    f32x4 acc00 = {}, acc01 = {}, acc10 = {}, acc11 = {};
    // staging: wave w covers rows 16w..16w+15 in two 8-row async ops per matrix
    int srow = 16 * w + (lane >> 3);       // +8 for the second op
    int scol = (lane & 7) * 8;             // shorts
    const short* Ag = &A[(size_t)(m0 + srow) * K + scol];
    const short* Bg = &Bt[(size_t)(n0 + srow) * K + scol];
    for (int k0 = kbeg; k0 < kend; k0 += 64) {
        __syncthreads();  // previous chunk's compute done before overwrite
        load16_lds(Ag + k0, &As[16 * w][0]);
        load16_lds(Ag + (size_t)8 * K + k0, &As[16 * w + 8][0]);
        load16_lds(Bg + k0, &Bs[16 * w][0]);
        load16_lds(Bg + (size_t)8 * K + k0, &Bs[16 * w + 8][0]);
        __syncthreads();  // vmcnt(0) drain inserted by compiler before barrier
#pragma unroll
        for (int kk = 0; kk < 64; kk += 32) {
            bf16x8 a0 = *(const bf16x8*)&As[mo + r][kk + quad * 8];
            bf16x8 a1 = *(const bf16x8*)&As[mo + 16 + r][kk + quad * 8];
            bf16x8 b0 = *(const bf16x8*)&Bs[no + r][kk + quad * 8];
            bf16x8 b1 = *(const bf16x8*)&Bs[no + 16 + r][kk + quad * 8];
            acc00 = __builtin_amdgcn_mfma_f32_16x16x32_bf16(a0, b0, acc00, 0, 0, 0);
            acc01 = __builtin_amdgcn_mfma_f32_16x16x32_bf16(a0, b1, acc01, 0, 0, 0);
            acc10 = __builtin_amdgcn_mfma_f32_16x16x32_bf16(a1, b0, acc10, 0, 0, 0);
            acc11 = __builtin_amdgcn_mfma_f32_16x16x32_bf16(a1, b1, acc11, 0, 0, 0);
        }
    }
#pragma unroll
    for (int i = 0; i < 2; ++i) {
#pragma unroll
        for (int j = 0; j < 2; ++j) {
            f32x4 acc = (i == 0) ? (j == 0 ? acc00 : acc01) : (j == 0 ? acc10 : acc11);
            int col = n0 + no + j * 16 + r;
            float bval = HAS_BIAS ? bias[col] : 0.f;
#pragma unroll
            for (int p = 0; p < 4; ++p) {
                int row = m0 + mo + i * 16 + quad * 4 + p;
                float v = acc[p];
                if (EPI == 0) {
                    Cf[(size_t)row * Nout + col] = v;
                } else if (EPI == 1) {
                    Cb[(size_t)row * Nout + col] = f2b(fmaxf(v + bval, 0.f));
                } else if (EPI == 2) {
                    float add = v + ((HAS_BIAS && kz == 0) ? bval : 0.f);
                    atomicAdd(&Cf[(size_t)row * Nout + col], add);
                } else if (EPI == 3) {
                    Cf[(size_t)row * Nout + col] = v + bval;
                } else if (EPI == 4) {
                    Cb[(size_t)row * Nout + col] = f2b(v);
                } else {
                    ((_Float16*)Cb)[(size_t)row * Nout + col] = (_Float16)v;
                }
            }
        }
    }
}

// fused Q/K/V projection: q,k -> bf16; v -> f16 (PV mfma uses f16)
__global__ __launch_bounds__(256) void gemm_qkv(const short* __restrict__ A, const short* __restrict__ wq,
                                                const short* __restrict__ wk, const short* __restrict__ wv,
                                                short* __restrict__ q, short* __restrict__ k,
                                                short* __restrict__ v, int M, int K, int Nout) {
    __shared__ short As[64][64];
    __shared__ short Bs[64][64];
    if (blockIdx.z == 0)
        gemm_body<4, false>(As, Bs, A, wq, nullptr, nullptr, q, M, K, Nout, 0, K, 0);
    else if (blockIdx.z == 1)
        gemm_body<4, false>(As, Bs, A, wk, nullptr, nullptr, k, M, K, Nout, 0, K, 0);
    else
        gemm_body<5, false>(As, Bs, A, wv, nullptr, nullptr, v, M, K, Nout, 0, K, 0);
}

template <int SPLITK, bool HAS_BIAS>
__global__ __launch_bounds__(256) void gemm_accum(const short* __restrict__ A, const short* __restrict__ Bt,
                                                  const float* __restrict__ bias, float* __restrict__ C,
                                                  int M, int K, int Nout) {
    __shared__ short As[64][64];
    __shared__ short Bs[64][64];
    int Kp = K / SPLITK;
    int kz = blockIdx.z;
    gemm_body<2, HAS_BIAS>(As, Bs, A, Bt, bias, C, nullptr, M, K, Nout, kz * Kp, kz * Kp + Kp, kz);
}

__global__ __launch_bounds__(256) void gemm_biasrelu_bf16(const short* __restrict__ A,
                                                          const short* __restrict__ Bt,
                                                          const float* __restrict__ bias,
                                                          short* __restrict__ C, int M, int K, int Nout) {
    __shared__ short As[64][64];
    __shared__ short Bs[64][64];
    gemm_body<1, true>(As, Bs, A, Bt, bias, nullptr, C, M, K, Nout, 0, K, 0);
}

__global__ __launch_bounds__(256) void gemm_bias(const short* __restrict__ A, const short* __restrict__ Bt,
                                                 const float* __restrict__ bias, float* __restrict__ C,
                                                 int M, int K, int Nout) {
    __shared__ short As[64][64];
    __shared__ short Bs[64][64];
    gemm_body<3, true>(As, Bs, A, Bt, bias, C, nullptr, M, K, Nout, 0, K, 0);
}

// MFMA flash attention. One wave (64 thr) per (b,h,q-tile of 16 queries).
// S^T = K·Q^T via mfma_16x16x32_bf16 -> C layout (q=lane&15, src=quad*4+reg)
// which IS the A-layout of mfma_16x16x16f16 -> PV with no transpose.
__global__ __launch_bounds__(64) void attn_kernel(const short* __restrict__ q,
                                                  const short* __restrict__ k,
                                                  const _Float16* __restrict__ v,
                                                  short* __restrict__ z) {
    int blk = blockIdx.x;
    int bh = blk & 63;
    int qt = 15 - (blk >> 6);  // heavy q-tiles dispatched first
    int b = bh >> 3, h = bh & 7;
    int lane = threadIdx.x;
    int r = lane & 15, quad = lane >> 4;
    int row0 = b * L_;

    bf16x8 qf = *(const bf16x8*)&q[(size_t)(row0 + qt * 16 + r) * D_ + h * DK_ + quad * 8];
    f32x4 O0 = {}, O1 = {};
    float mA = -1e30f, den = 0.f;
    int nk = qt + 1;

    bf16x8 kf = *(const bf16x8*)&k[(size_t)(row0 + r) * D_ + h * DK_ + quad * 8];
    f16x4 va, vb;
    {
        const _Float16* vp = v + (size_t)(row0 + quad * 4) * D_ + h * DK_;
#pragma unroll
        for (int i = 0; i < 4; ++i) {
            va[i] = vp[(size_t)i * D_ + r];
            vb[i] = vp[(size_t)i * D_ + 16 + r];
        }
    }
    for (int kt = 0; kt < nk; ++kt) {
        bf16x8 kf_n = kf;
        f16x4 va_n = va, vb_n = vb;
        if (kt + 1 < nk) {
            kf_n = *(const bf16x8*)&k[(size_t)(row0 + (kt + 1) * 16 + r) * D_ + h * DK_ + quad * 8];
            const _Float16* vp = v + (size_t)(row0 + (kt + 1) * 16 + quad * 4) * D_ + h * DK_;
#pragma unroll
            for (int i = 0; i < 4; ++i) {
                va_n[i] = vp[(size_t)i * D_ + r];
                vb_n[i] = vp[(size_t)i * D_ + 16 + r];
            }
        }
        f32x4 zero = {};
        f32x4 s = __builtin_amdgcn_mfma_f32_16x16x32_bf16(kf, qf, zero, 0, 0, 0);
#pragma unroll
        for (int i2 = 0; i2 < 4; ++i2) s[i2] *= 0.17677669529663687f;
        if (kt == qt) {
#pragma unroll
            for (int i2 = 0; i2 < 4; ++i2)
                if (quad * 4 + i2 > r) s[i2] = -1e30f;
        }
        float tmax = fmaxf(fmaxf(s[0], s[1]), fmaxf(s[2], s[3]));
        tmax = fmaxf(tmax, __shfl_xor(tmax, 16, 64));
        tmax = fmaxf(tmax, __shfl_xor(tmax, 32, 64));
        float mn = fmaxf(mA, tmax);
        float alpha = __expf(mA - mn);
        mA = mn;
        float p0 = __expf(s[0] - mn), p1 = __expf(s[1] - mn);
        float p2 = __expf(s[2] - mn), p3 = __expf(s[3] - mn);
        float ts = (p0 + p1) + (p2 + p3);
        ts += __shfl_xor(ts, 16, 64);
        ts += __shfl_xor(ts, 32, 64);
        den = den * alpha + ts;
        f16x4 pf;
        pf[0] = (_Float16)p0; pf[1] = (_Float16)p1; pf[2] = (_Float16)p2; pf[3] = (_Float16)p3;
        float al[4];
#pragma unroll
        for (int i2 = 0; i2 < 4; ++i2) al[i2] = __shfl(alpha, quad * 4 + i2, 64);
#pragma unroll
        for (int i2 = 0; i2 < 4; ++i2) { O0[i2] *= al[i2]; O1[i2] *= al[i2]; }
        O0 = __builtin_amdgcn_mfma_f32_16x16x16f16(pf, va, O0, 0, 0, 0);
        O1 = __builtin_amdgcn_mfma_f32_16x16x16f16(pf, vb, O1, 0, 0, 0);
        kf = kf_n; va = va_n; vb = vb_n;
    }
#pragma unroll
    for (int i2 = 0; i2 < 4; ++i2) {
        float inv = 1.0f / __shfl(den, quad * 4 + i2, 64);
        int rowz = row0 + qt * 16 + quad * 4 + i2;
        z[(size_t)rowz * D_ + h * DK_ + r] = f2b(O0[i2] * inv);
        z[(size_t)rowz * D_ + h * DK_ + 16 + r] = f2b(O1[i2] * inv);
    }
}

// in-place log_softmax over V=2048, one block per row
__global__ void lsm_kernel(float* __restrict__ logits) {
    __shared__ float rm[4], rs[4];
    int row = blockIdx.x, t = threadIdx.x;
    float* p = logits + (size_t)row * V_;
    float vals[8];
    float mx = -INFINITY;
#pragma unroll
    for (int i = 0; i < 8; ++i) {
        vals[i] = p[t + i * 256];
        mx = fmaxf(mx, vals[i]);
    }
#pragma unroll
    for (int off = 32; off; off >>= 1) mx = fmaxf(mx, __shfl_xor(mx, off, 64));
    int w = t >> 6;
    if ((t & 63) == 0) rm[w] = mx;
    __syncthreads();
    mx = fmaxf(fmaxf(rm[0], rm[1]), fmaxf(rm[2], rm[3]));
    float s = 0.f;
#pragma unroll
    for (int i = 0; i < 8; ++i) s += __expf(vals[i] - mx);
#pragma unroll
    for (int off = 32; off; off >>= 1) s += __shfl_xor(s, off, 64);
    if ((t & 63) == 0) rs[w] = s;
    __syncthreads();
    s = rs[0] + rs[1] + rs[2] + rs[3];
    float lse = mx + logf(s);
#pragma unroll
    for (int i = 0; i < 8; ++i) p[t + i * 256] = vals[i] - lse;
}

extern "C" void kernel_launch(void* const* d_in, const int* in_sizes, int n_in,
                              void* d_out, int out_size, void* d_ws, size_t ws_size,
                              hipStream_t stream) {
    const int* tokens = (const int*)d_in[0];
    const int* positions = (const int*)d_in[1];
    // d_in[2]=src, d_in[3]=dst: deterministic causal structure — unused
    const float* vtab = (const float*)d_in[4];
    const float* ctab = (const float*)d_in[5];
    const float* ptab = (const float*)d_in[6];
    const float* ln1_g = (const float*)d_in[7];
    const float* ln1_b = (const float*)d_in[8];
    const float* Wq = (const float*)d_in[9];
    const float* Wk = (const float*)d_in[10];
    const float* Wv = (const float*)d_in[11];
    const float* Wo = (const float*)d_in[12];
    const float* ln2_g = (const float*)d_in[13];
    const float* ln2_b = (const float*)d_in[14];
    const float* W1 = (const float*)d_in[15];
    const float* b1 = (const float*)d_in[16];
    const float* W2 = (const float*)d_in[17];
    const float* b2 = (const float*)d_in[18];
    const float* lnf_g = (const float*)d_in[19];
    const float* lnf_b = (const float*)d_in[20];
    const float* Wgen = (const float*)d_in[21];
    const float* bgen = (const float*)d_in[22];

    char* p = (char*)d_ws;
    float* x = (float*)p;      p += (size_t)N_ * D_ * 4;
    short* qb = (short*)p;     p += (size_t)N_ * D_ * 4;   // bf16 (padded alloc)
    short* kb = (short*)p;     p += (size_t)N_ * D_ * 4;   // bf16
    short* vbh = (short*)p;    p += (size_t)N_ * D_ * 4;   // f16
    short* xnb = (short*)p;    p += (size_t)N_ * D_ * 2;
    short* zbb = (short*)p;    p += (size_t)N_ * D_ * 2;
    short* hbb = (short*)p;    p += (size_t)N_ * FF_ * 2;
    short* wqT = (short*)p;    p += (size_t)NL_ * D_ * D_ * 2;
    short* wkT = (short*)p;    p += (size_t)NL_ * D_ * D_ * 2;
    short* wvT = (short*)p;    p += (size_t)NL_ * D_ * D_ * 2;
    short* woT = (short*)p;    p += (size_t)NL_ * D_ * D_ * 2;
    short* w1T = (short*)p;    p += (size_t)NL_ * D_ * FF_ * 2;
    short* w2T = (short*)p;    p += (size_t)NL_ * FF_ * D_ * 2;
    short* wgT = (short*)p;    p += (size_t)D_ * V_ * 2;
    float* out = (float*)d_out;

    dim3 tb(32, 8);
    transpose_w4<<<dim3(8, 8, 16), tb, 0, stream>>>(Wq, Wk, Wv, Wo, wqT, wkT, wvT, woT);
    transpose_w<<<dim3(32, 8, NL_), tb, 0, stream>>>(W1, w1T, D_, FF_);
    transpose_w<<<dim3(8, 32, NL_), tb, 0, stream>>>(W2, w2T, FF_, D_);
    transpose_w<<<dim3(64, 8, 1), tb, 0, stream>>>(Wgen, wgT, D_, V_);

    embed_kernel<<<N_, 256, 0, stream>>>(tokens, positions, vtab, ctab, ptab, x);
    dim3 gQKV(N_ / 64, D_ / 64, 3);   // 384 blocks
    dim3 gWo(N_ / 64, D_ / 64, 4);    // 512 blocks, split-K 4 (Kp=64)
    dim3 gW1(N_ / 64, FF_ / 64);      // 512 blocks
    dim3 gW2(N_ / 64, D_ / 64, 8);    // 1024 blocks, split-K 8 (Kp=128)
    dim3 gGen(N_ / 64, V_ / 64);      // 1024 blocks
    for (int i = 0; i < NL_; ++i) {
        ln_kernel<<<N_, 256, 0, stream>>>(x, ln1_g + i * D_, ln1_b + i * D_, xnb);
        gemm_qkv<<<gQKV, 256, 0, stream>>>(xnb, wqT + (size_t)i * D_ * D_, wkT + (size_t)i * D_ * D_,
                                           wvT + (size_t)i * D_ * D_, qb, kb, vbh, N_, D_, D_);
        attn_kernel<<<B_ * H_ * 16, 64, 0, stream>>>(qb, kb, (const _Float16*)vbh, zbb);
        gemm_accum<4, false><<<gWo, 256, 0, stream>>>(zbb, woT + (size_t)i * D_ * D_, nullptr, x, N_, D_, D_);
        ln_kernel<<<N_, 256, 0, stream>>>(x, ln2_g + i * D_, ln2_b + i * D_, xnb);
        gemm_biasrelu_bf16<<<gW1, 256, 0, stream>>>(xnb, w1T + (size_t)i * D_ * FF_, b1 + (size_t)i * FF_,
                                                    hbb, N_, D_, FF_);
        gemm_accum<8, true><<<gW2, 256, 0, stream>>>(hbb, w2T + (size_t)i * FF_ * D_, b2 + (size_t)i * D_,
                                                     x, N_, FF_, D_);
    }
    ln_kernel<<<N_, 256, 0, stream>>>(x, lnf_g, lnf_b, xnb);
    gemm_bias<<<gGen, 256, 0, stream>>>(xnb, wgT, bgen, out, N_, D_, V_);
    lsm_kernel<<<N_, 256, 0, stream>>>(out);
}